// Round 1
// baseline (1304.246 us; speedup 1.0000x reference)
//
#include <hip/hip_runtime.h>
#include <hip/hip_bf16.h>
#include <math.h>
#include <stdint.h>

#define NNODES 50000
#define NEDGES 800000
#define DIM 256
#define HEADS 4
#define DH 64
#define NEG_SLOPE 0.2f

// ---------------- GEMM: C[M,256] = A[M,256] @ B[256,256], fp32 ----------------
// block = 256 threads, tile = 32 rows x 256 cols, K-tiles of 32.
// Thread (ty=t>>6, tx=t&63) computes 8 rows x 4 cols register tile.
// A tile stored transposed in LDS so fragment reads are b128 / wave-broadcast.
__global__ __launch_bounds__(256) void gemm_k(const float* __restrict__ A,
                                              const float* __restrict__ B,
                                              float* __restrict__ C, int M) {
  __shared__ float Ast[32][36];   // [k][row], +4 pad keeps rows 16B-aligned
  __shared__ float Bs[32][256];   // [k][col]
  int t = threadIdx.x;
  int tx = t & 63;
  int ty = t >> 6;
  int row0 = blockIdx.x * 32;
  float acc[8][4];
#pragma unroll
  for (int i = 0; i < 8; ++i)
#pragma unroll
    for (int j = 0; j < 4; ++j) acc[i][j] = 0.f;

  int ar = t >> 3, ak = (t & 7) * 4;   // A staging: row ar, k-cols ak..ak+3
  int bc = (t & 63) * 4, bk = t >> 6;  // B staging: col bc..bc+3, k-row bk

  for (int k0 = 0; k0 < DIM; k0 += 32) {
    float4 av = make_float4(0.f, 0.f, 0.f, 0.f);
    if (row0 + ar < M) av = *(const float4*)&A[(size_t)(row0 + ar) * DIM + k0 + ak];
    Ast[ak + 0][ar] = av.x;
    Ast[ak + 1][ar] = av.y;
    Ast[ak + 2][ar] = av.z;
    Ast[ak + 3][ar] = av.w;
#pragma unroll
    for (int kk = 0; kk < 32; kk += 4) {
      float4 bv = *(const float4*)&B[(size_t)(k0 + bk + kk) * DIM + bc];
      *(float4*)&Bs[bk + kk][bc] = bv;
    }
    __syncthreads();
#pragma unroll
    for (int k = 0; k < 32; ++k) {
      float b0[4], a0[8];
      *(float4*)&b0[0] = *(const float4*)&Bs[k][tx * 4];
      *(float4*)&a0[0] = *(const float4*)&Ast[k][ty * 8];
      *(float4*)&a0[4] = *(const float4*)&Ast[k][ty * 8 + 4];
#pragma unroll
      for (int i = 0; i < 8; ++i)
#pragma unroll
        for (int j = 0; j < 4; ++j) acc[i][j] += a0[i] * b0[j];
    }
    __syncthreads();
  }
#pragma unroll
  for (int i = 0; i < 8; ++i) {
    int r = row0 + ty * 8 + i;
    if (r < M)
      *(float4*)&C[(size_t)r * DIM + tx * 4] =
          make_float4(acc[i][0], acc[i][1], acc[i][2], acc[i][3]);
  }
}

// --------------- el/er: per (node, head) dot of feat with al/ar ---------------
// block = 256 = 4 waves; wave w = head w of node blockIdx.x; lane = feature dim.
__global__ __launch_bounds__(256) void lr_k(const float* __restrict__ feat,
                                            const float* __restrict__ al,
                                            const float* __restrict__ ar,
                                            float* __restrict__ el,
                                            float* __restrict__ er) {
  int n = blockIdx.x;
  int lane = threadIdx.x & 63;
  int w = threadIdx.x >> 6;
  float f = feat[(size_t)n * DIM + w * DH + lane];
  float a = f * al[w * DH + lane];
  float b = f * ar[w * DH + lane];
#pragma unroll
  for (int off = 32; off > 0; off >>= 1) {
    a += __shfl_down(a, off, 64);
    b += __shfl_down(b, off, 64);
  }
  if (lane == 0) {
    el[n * HEADS + w] = a;
    er[n * HEADS + w] = b;
  }
}

// ---------------- CSR build ----------------
__global__ __launch_bounds__(256) void deg_k(const int* __restrict__ dst,
                                             int* __restrict__ deg) {
  int e = blockIdx.x * 256 + threadIdx.x;
  if (e < NEDGES) atomicAdd(&deg[dst[e]], 1);
}

// single-block exclusive scan, 1024 threads, 4 elems/thread per chunk
__global__ __launch_bounds__(1024) void scan_k(const int* __restrict__ deg,
                                               int* __restrict__ row_ptr,
                                               int* __restrict__ cursor, int n) {
  __shared__ int wsum[16];
  __shared__ int wpref[16];
  int t = threadIdx.x, lane = t & 63, w = t >> 6;
  int running = 0;
  for (int base = 0; base < n; base += 4096) {
    int idx0 = base + t * 4;
    int4 v = make_int4(0, 0, 0, 0);
    if (idx0 + 3 < n) v = *(const int4*)&deg[idx0];
    else {
      if (idx0 < n) v.x = deg[idx0];
      if (idx0 + 1 < n) v.y = deg[idx0 + 1];
      if (idx0 + 2 < n) v.z = deg[idx0 + 2];
    }
    int s0 = v.x, s1 = s0 + v.y, s2 = s1 + v.z, s3 = s2 + v.w;
    int incl = s3;
#pragma unroll
    for (int off = 1; off < 64; off <<= 1) {
      int u = __shfl_up(incl, off, 64);
      if (lane >= off) incl += u;
    }
    if (lane == 63) wsum[w] = incl;
    __syncthreads();
    if (w == 0 && lane < 16) {
      int x = wsum[lane];
#pragma unroll
      for (int off = 1; off < 16; off <<= 1) {
        int u = __shfl_up(x, off, 64);
        if (lane >= off) x += u;
      }
      wpref[lane] = x;
    }
    __syncthreads();
    int wbase = (w == 0) ? 0 : wpref[w - 1];
    int texcl = incl - s3 + wbase + running;
    if (idx0 < n)     { row_ptr[idx0]     = texcl;      cursor[idx0]     = texcl; }
    if (idx0 + 1 < n) { row_ptr[idx0 + 1] = texcl + s0; cursor[idx0 + 1] = texcl + s0; }
    if (idx0 + 2 < n) { row_ptr[idx0 + 2] = texcl + s1; cursor[idx0 + 2] = texcl + s1; }
    if (idx0 + 3 < n) { row_ptr[idx0 + 3] = texcl + s2; cursor[idx0 + 3] = texcl + s2; }
    int tot = wpref[15];
    __syncthreads();
    running += tot;
  }
  if (t == 0) row_ptr[n] = running;
}

__global__ __launch_bounds__(256) void scatter_k(const int* __restrict__ dst,
                                                 int* __restrict__ cursor,
                                                 int* __restrict__ eidx) {
  int e = blockIdx.x * 256 + threadIdx.x;
  if (e < NEDGES) {
    int pos = atomicAdd(&cursor[dst[e]], 1);
    eidx[pos] = e;
  }
}

// -------- edge scores: ex = exp(leaky_relu(el[src]+er[dst])), denom scatter ----
// NOTE: segment_max subtraction is dropped — scores are O(1), exp cannot
// overflow in fp32, and alpha = ex/sum(ex) is identical either way.
__global__ __launch_bounds__(256) void score_k(const int* __restrict__ src,
                                               const int* __restrict__ dst,
                                               const float* __restrict__ el,
                                               const float* __restrict__ er,
                                               float* __restrict__ ex,
                                               float* __restrict__ denom) {
  int e = blockIdx.x * 256 + threadIdx.x;
  if (e >= NEDGES) return;
  int s = src[e], d = dst[e];
  float4 l = *(const float4*)&el[s * HEADS];
  float4 r = *(const float4*)&er[d * HEADS];
  float4 o;
  float v;
  v = l.x + r.x; v = v > 0.f ? v : NEG_SLOPE * v; o.x = __expf(v);
  v = l.y + r.y; v = v > 0.f ? v : NEG_SLOPE * v; o.y = __expf(v);
  v = l.z + r.z; v = v > 0.f ? v : NEG_SLOPE * v; o.z = __expf(v);
  v = l.w + r.w; v = v > 0.f ? v : NEG_SLOPE * v; o.w = __expf(v);
  *(float4*)&ex[(size_t)e * HEADS] = o;
  atomicAdd(&denom[d * HEADS + 0], o.x);
  atomicAdd(&denom[d * HEADS + 1], o.y);
  atomicAdd(&denom[d * HEADS + 2], o.z);
  atomicAdd(&denom[d * HEADS + 3], o.w);
}

// ---------------- aggregation layer 1 (gather over CSR) + ELU ----------------
// block = 256 = 4 waves; wave w = head; lane = feature dim within head.
__global__ __launch_bounds__(256) void agg1_k(const float* __restrict__ feat,
                                              const float* __restrict__ ex,
                                              const float* __restrict__ denom,
                                              const int* __restrict__ row_ptr,
                                              const int* __restrict__ eidx,
                                              const int* __restrict__ src,
                                              float* __restrict__ hout) {
  int n = blockIdx.x;
  int lane = threadIdx.x & 63;
  int w = threadIdx.x >> 6;
  int beg = row_ptr[n], end = row_ptr[n + 1];
  float inv = 1.0f / fmaxf(denom[n * HEADS + w], 1e-9f);
  float acc = 0.f;
  for (int i = beg; i < end; ++i) {
    int e = eidx[i];
    int s = src[e];
    float a = ex[(size_t)e * HEADS + w] * inv;
    acc += feat[(size_t)s * DIM + w * DH + lane] * a;
  }
  acc = acc > 0.f ? acc : (__expf(acc) - 1.f);  // ELU
  hout[(size_t)n * DIM + w * DH + lane] = acc;
}

// ------------- aggregation layer 2 + mean over heads -> d_out[N,64] ----------
__global__ __launch_bounds__(256) void agg2_k(const float* __restrict__ feat,
                                              const float* __restrict__ ex,
                                              const float* __restrict__ denom,
                                              const int* __restrict__ row_ptr,
                                              const int* __restrict__ eidx,
                                              const int* __restrict__ src,
                                              float* __restrict__ out) {
  __shared__ float sm[HEADS][DH];
  int n = blockIdx.x;
  int lane = threadIdx.x & 63;
  int w = threadIdx.x >> 6;
  int beg = row_ptr[n], end = row_ptr[n + 1];
  float inv = 1.0f / fmaxf(denom[n * HEADS + w], 1e-9f);
  float acc = 0.f;
  for (int i = beg; i < end; ++i) {
    int e = eidx[i];
    int s = src[e];
    float a = ex[(size_t)e * HEADS + w] * inv;
    acc += feat[(size_t)s * DIM + w * DH + lane] * a;
  }
  sm[w][lane] = acc;
  __syncthreads();
  if (w == 0) {
    float m = (sm[0][lane] + sm[1][lane] + sm[2][lane] + sm[3][lane]) * 0.25f;
    out[(size_t)n * DH + lane] = m;
  }
}

extern "C" void kernel_launch(void* const* d_in, const int* in_sizes, int n_in,
                              void* d_out, int out_size, void* d_ws, size_t ws_size,
                              hipStream_t stream) {
  const float* feature = (const float*)d_in[0];
  const float* W1 = (const float*)d_in[1];
  const float* al1 = (const float*)d_in[2];
  const float* ar1 = (const float*)d_in[3];
  const float* W2 = (const float*)d_in[4];
  const float* al2 = (const float*)d_in[5];
  const float* ar2 = (const float*)d_in[6];
  const int* src = (const int*)d_in[7];
  const int* dst = (const int*)d_in[8];
  float* out = (float*)d_out;

  uintptr_t p = (uintptr_t)d_ws;
  auto alloc = [&](size_t bytes) -> void* {
    uintptr_t cur = (p + 255) & ~(uintptr_t)255;
    p = cur + bytes;
    return (void*)cur;
  };
  float* featA = (float*)alloc((size_t)NNODES * DIM * 4);       // 51.2 MB
  float* hbuf  = (float*)alloc((size_t)NNODES * DIM * 4);       // 51.2 MB
  float* exbuf = (float*)alloc((size_t)NEDGES * HEADS * 4);     // 12.8 MB
  float* el    = (float*)alloc((size_t)NNODES * HEADS * 4);
  float* er    = (float*)alloc((size_t)NNODES * HEADS * 4);
  float* denom = (float*)alloc((size_t)NNODES * HEADS * 4);
  int* deg     = (int*)alloc((size_t)NNODES * 4);
  int* row_ptr = (int*)alloc((size_t)(NNODES + 1) * 4);
  int* cursor  = (int*)alloc((size_t)NNODES * 4);
  int* eidx    = (int*)alloc((size_t)NEDGES * 4);

  const int EB = (NEDGES + 255) / 256;
  const int MB = (NNODES + 31) / 32;

  // ---- CSR by dst (same graph for both layers) ----
  hipMemsetAsync(deg, 0, (size_t)NNODES * 4, stream);
  deg_k<<<EB, 256, 0, stream>>>(dst, deg);
  scan_k<<<1, 1024, 0, stream>>>(deg, row_ptr, cursor, NNODES);
  scatter_k<<<EB, 256, 0, stream>>>(dst, cursor, eidx);

  // ---- layer 1 ----
  gemm_k<<<MB, 256, 0, stream>>>(feature, W1, featA, NNODES);
  lr_k<<<NNODES, 256, 0, stream>>>(featA, al1, ar1, el, er);
  hipMemsetAsync(denom, 0, (size_t)NNODES * HEADS * 4, stream);
  score_k<<<EB, 256, 0, stream>>>(src, dst, el, er, exbuf, denom);
  agg1_k<<<NNODES, 256, 0, stream>>>(featA, exbuf, denom, row_ptr, eidx, src, hbuf);

  // ---- layer 2 (featA reused as feat2) ----
  gemm_k<<<MB, 256, 0, stream>>>(hbuf, W2, featA, NNODES);
  lr_k<<<NNODES, 256, 0, stream>>>(featA, al2, ar2, el, er);
  hipMemsetAsync(denom, 0, (size_t)NNODES * HEADS * 4, stream);
  score_k<<<EB, 256, 0, stream>>>(src, dst, el, er, exbuf, denom);
  agg2_k<<<NNODES, 256, 0, stream>>>(featA, exbuf, denom, row_ptr, eidx, src, out);
}

// Round 2
// 638.991 us; speedup vs baseline: 2.0411x; 2.0411x over previous
//
#include <hip/hip_runtime.h>
#include <hip/hip_bf16.h>
#include <math.h>
#include <stdint.h>

#define NNODES 50000
#define NEDGES 800000
#define DIM 256
#define HEADS 4
#define DH 64
#define NEG_SLOPE 0.2f

static __device__ __forceinline__ unsigned short f2bf(float x) {
  unsigned int u = __float_as_uint(x);
  unsigned int r = (u + 0x7fffu + ((u >> 16) & 1u)) >> 16;
  return (unsigned short)r;
}
static __device__ __forceinline__ float bf2f(unsigned short h) {
  return __uint_as_float(((unsigned int)h) << 16);
}

// ---------------- GEMM: Cb[M,256](bf16) = A[M,256](f32) @ B[256,256](f32) ----
// block = 256 threads, tile = 32 rows x 256 cols, K-tiles of 32.
// Thread (ty=t>>6, tx=t&63) computes 8 rows x 4 cols register tile.
__global__ __launch_bounds__(256) void gemm_k(const float* __restrict__ A,
                                              const float* __restrict__ B,
                                              unsigned short* __restrict__ Cb,
                                              int M) {
  __shared__ float Ast[32][36];   // [k][row], +4 pad keeps rows 16B-aligned
  __shared__ float Bs[32][256];   // [k][col]
  int t = threadIdx.x;
  int tx = t & 63;
  int ty = t >> 6;
  int row0 = blockIdx.x * 32;
  float acc[8][4];
#pragma unroll
  for (int i = 0; i < 8; ++i)
#pragma unroll
    for (int j = 0; j < 4; ++j) acc[i][j] = 0.f;

  int ar = t >> 3, ak = (t & 7) * 4;   // A staging: row ar, k-cols ak..ak+3
  int bc = (t & 63) * 4, bk = t >> 6;  // B staging: col bc..bc+3, k-row bk

  for (int k0 = 0; k0 < DIM; k0 += 32) {
    float4 av = make_float4(0.f, 0.f, 0.f, 0.f);
    if (row0 + ar < M) av = *(const float4*)&A[(size_t)(row0 + ar) * DIM + k0 + ak];
    Ast[ak + 0][ar] = av.x;
    Ast[ak + 1][ar] = av.y;
    Ast[ak + 2][ar] = av.z;
    Ast[ak + 3][ar] = av.w;
#pragma unroll
    for (int kk = 0; kk < 32; kk += 4) {
      float4 bv = *(const float4*)&B[(size_t)(k0 + bk + kk) * DIM + bc];
      *(float4*)&Bs[bk + kk][bc] = bv;
    }
    __syncthreads();
#pragma unroll
    for (int k = 0; k < 32; ++k) {
      float b0[4], a0[8];
      *(float4*)&b0[0] = *(const float4*)&Bs[k][tx * 4];
      *(float4*)&a0[0] = *(const float4*)&Ast[k][ty * 8];
      *(float4*)&a0[4] = *(const float4*)&Ast[k][ty * 8 + 4];
#pragma unroll
      for (int i = 0; i < 8; ++i)
#pragma unroll
        for (int j = 0; j < 4; ++j) acc[i][j] += a0[i] * b0[j];
    }
    __syncthreads();
  }
#pragma unroll
  for (int i = 0; i < 8; ++i) {
    int r = row0 + ty * 8 + i;
    if (r < M) {
      ushort4 o;
      o.x = f2bf(acc[i][0]);
      o.y = f2bf(acc[i][1]);
      o.z = f2bf(acc[i][2]);
      o.w = f2bf(acc[i][3]);
      *(ushort4*)&Cb[(size_t)r * DIM + tx * 4] = o;
    }
  }
}

// --------------- el/er: per (node, head) dot of feat(bf16) with al/ar --------
__global__ __launch_bounds__(256) void lr_k(const unsigned short* __restrict__ feat,
                                            const float* __restrict__ al,
                                            const float* __restrict__ ar,
                                            float* __restrict__ el,
                                            float* __restrict__ er) {
  int n = blockIdx.x;
  int lane = threadIdx.x & 63;
  int w = threadIdx.x >> 6;
  float f = bf2f(feat[(size_t)n * DIM + w * DH + lane]);
  float a = f * al[w * DH + lane];
  float b = f * ar[w * DH + lane];
#pragma unroll
  for (int off = 32; off > 0; off >>= 1) {
    a += __shfl_down(a, off, 64);
    b += __shfl_down(b, off, 64);
  }
  if (lane == 0) {
    el[n * HEADS + w] = a;
    er[n * HEADS + w] = b;
  }
}

// ---------------- CSR build ----------------
__global__ __launch_bounds__(256) void deg_k(const int* __restrict__ dst,
                                             int* __restrict__ deg) {
  int e = blockIdx.x * 256 + threadIdx.x;
  if (e < NEDGES) atomicAdd(&deg[dst[e]], 1);
}

// single-block exclusive scan, 1024 threads, 4 elems/thread per chunk
__global__ __launch_bounds__(1024) void scan_k(const int* __restrict__ deg,
                                               int* __restrict__ row_ptr,
                                               int* __restrict__ cursor, int n) {
  __shared__ int wsum[16];
  __shared__ int wpref[16];
  int t = threadIdx.x, lane = t & 63, w = t >> 6;
  int running = 0;
  for (int base = 0; base < n; base += 4096) {
    int idx0 = base + t * 4;
    int4 v = make_int4(0, 0, 0, 0);
    if (idx0 + 3 < n) v = *(const int4*)&deg[idx0];
    else {
      if (idx0 < n) v.x = deg[idx0];
      if (idx0 + 1 < n) v.y = deg[idx0 + 1];
      if (idx0 + 2 < n) v.z = deg[idx0 + 2];
    }
    int s0 = v.x, s1 = s0 + v.y, s2 = s1 + v.z, s3 = s2 + v.w;
    int incl = s3;
#pragma unroll
    for (int off = 1; off < 64; off <<= 1) {
      int u = __shfl_up(incl, off, 64);
      if (lane >= off) incl += u;
    }
    if (lane == 63) wsum[w] = incl;
    __syncthreads();
    if (w == 0 && lane < 16) {
      int x = wsum[lane];
#pragma unroll
      for (int off = 1; off < 16; off <<= 1) {
        int u = __shfl_up(x, off, 64);
        if (lane >= off) x += u;
      }
      wpref[lane] = x;
    }
    __syncthreads();
    int wbase = (w == 0) ? 0 : wpref[w - 1];
    int texcl = incl - s3 + wbase + running;
    if (idx0 < n)     { row_ptr[idx0]     = texcl;      cursor[idx0]     = texcl; }
    if (idx0 + 1 < n) { row_ptr[idx0 + 1] = texcl + s0; cursor[idx0 + 1] = texcl + s0; }
    if (idx0 + 2 < n) { row_ptr[idx0 + 2] = texcl + s1; cursor[idx0 + 2] = texcl + s1; }
    if (idx0 + 3 < n) { row_ptr[idx0 + 3] = texcl + s2; cursor[idx0 + 3] = texcl + s2; }
    int tot = wpref[15];
    __syncthreads();
    running += tot;
  }
  if (t == 0) row_ptr[n] = running;
}

// CSR scatter: also records srcs in CSR order and the edge->pos permutation.
__global__ __launch_bounds__(256) void scatter_k(const int* __restrict__ src,
                                                 const int* __restrict__ dst,
                                                 int* __restrict__ cursor,
                                                 int* __restrict__ srcs,
                                                 int* __restrict__ epos) {
  int e = blockIdx.x * 256 + threadIdx.x;
  if (e < NEDGES) {
    int pos = atomicAdd(&cursor[dst[e]], 1);
    srcs[pos] = src[e];
    epos[e] = pos;
  }
}

// -------- edge scores: ex = exp(leaky_relu(el[src]+er[dst])) written in CSR order
// segment_max subtraction dropped: scores are O(1) (|e| < ~10), exp is safe in
// fp32 and alpha = ex/sum(ex) is mathematically identical.
__global__ __launch_bounds__(256) void score_k(const int* __restrict__ src,
                                               const int* __restrict__ dst,
                                               const int* __restrict__ epos,
                                               const float* __restrict__ el,
                                               const float* __restrict__ er,
                                               float* __restrict__ excsr) {
  int e = blockIdx.x * 256 + threadIdx.x;
  if (e >= NEDGES) return;
  int s = src[e], d = dst[e];
  float4 l = *(const float4*)&el[s * HEADS];
  float4 r = *(const float4*)&er[d * HEADS];
  float4 o;
  float v;
  v = l.x + r.x; v = v > 0.f ? v : NEG_SLOPE * v; o.x = __expf(v);
  v = l.y + r.y; v = v > 0.f ? v : NEG_SLOPE * v; o.y = __expf(v);
  v = l.z + r.z; v = v > 0.f ? v : NEG_SLOPE * v; o.z = __expf(v);
  v = l.w + r.w; v = v > 0.f ? v : NEG_SLOPE * v; o.w = __expf(v);
  *(float4*)&excsr[(size_t)epos[e] * HEADS] = o;
}

// ---------------- aggregation (gather over CSR), branchless pipelined --------
// block = 256 = 4 waves; wave w = head. Chunk of 16 edges: lanes 0..15 load
// src + ex (zero-filled tail), broadcast by shuffle; each iteration processes
// 2 edges (lanes 0-31 even edge, 32-63 odd edge) with a ushort2 bf16 load
// (4 B/lane). 8 independent loads per chunk -> deep MLP. denom computed
// in-register as sum of ex (replaces the old atomics pass).
#define AGG_BODY(feat, excsr, row_ptr, srcs)                                     \
  int n = blockIdx.x;                                                            \
  int lane = threadIdx.x & 63;                                                   \
  int w = threadIdx.x >> 6;                                                      \
  int li = lane & 31;                                                            \
  int half = lane >> 5;                                                          \
  int beg = row_ptr[n], end = row_ptr[n + 1];                                    \
  float accx = 0.f, accy = 0.f, sume = 0.f;                                      \
  for (int c0 = beg; c0 < end; c0 += 16) {                                       \
    int s_l = 0;                                                                 \
    float e_l = 0.f;                                                             \
    if (lane < 16 && c0 + lane < end) {                                          \
      s_l = srcs[c0 + lane];                                                     \
      e_l = excsr[(size_t)(c0 + lane) * HEADS + w];                              \
    }                                                                            \
    _Pragma("unroll")                                                            \
    for (int j = 0; j < 8; ++j) {                                                \
      int idx = 2 * j + half;                                                    \
      int s = __shfl(s_l, idx, 64);                                              \
      float a = __shfl(e_l, idx, 64);                                            \
      ushort2 u = *(const ushort2*)&feat[(size_t)s * DIM + w * DH + li * 2];     \
      accx += bf2f(u.x) * a;                                                     \
      accy += bf2f(u.y) * a;                                                     \
      sume += a;                                                                 \
    }                                                                            \
  }                                                                              \
  accx += __shfl_xor(accx, 32, 64);                                              \
  accy += __shfl_xor(accy, 32, 64);                                              \
  sume += __shfl_xor(sume, 32, 64);                                              \
  float inv = 1.f / fmaxf(sume, 1e-9f);

__global__ __launch_bounds__(256) void agg1_k(const unsigned short* __restrict__ feat,
                                              const float* __restrict__ excsr,
                                              const int* __restrict__ row_ptr,
                                              const int* __restrict__ srcs,
                                              float* __restrict__ hout) {
  AGG_BODY(feat, excsr, row_ptr, srcs)
  if (half == 0) {
    float vx = accx * inv, vy = accy * inv;
    vx = vx > 0.f ? vx : (__expf(vx) - 1.f);  // ELU
    vy = vy > 0.f ? vy : (__expf(vy) - 1.f);
    *(float2*)&hout[(size_t)n * DIM + w * DH + li * 2] = make_float2(vx, vy);
  }
}

__global__ __launch_bounds__(256) void agg2_k(const unsigned short* __restrict__ feat,
                                              const float* __restrict__ excsr,
                                              const int* __restrict__ row_ptr,
                                              const int* __restrict__ srcs,
                                              float* __restrict__ out) {
  __shared__ float sm[HEADS][DH];
  AGG_BODY(feat, excsr, row_ptr, srcs)
  if (half == 0) {
    sm[w][li * 2] = accx * inv;
    sm[w][li * 2 + 1] = accy * inv;
  }
  __syncthreads();
  if (w == 0) {
    float m = (sm[0][lane] + sm[1][lane] + sm[2][lane] + sm[3][lane]) * 0.25f;
    out[(size_t)n * DH + lane] = m;
  }
}

extern "C" void kernel_launch(void* const* d_in, const int* in_sizes, int n_in,
                              void* d_out, int out_size, void* d_ws, size_t ws_size,
                              hipStream_t stream) {
  const float* feature = (const float*)d_in[0];
  const float* W1 = (const float*)d_in[1];
  const float* al1 = (const float*)d_in[2];
  const float* ar1 = (const float*)d_in[3];
  const float* W2 = (const float*)d_in[4];
  const float* al2 = (const float*)d_in[5];
  const float* ar2 = (const float*)d_in[6];
  const int* src = (const int*)d_in[7];
  const int* dst = (const int*)d_in[8];
  float* out = (float*)d_out;

  uintptr_t p = (uintptr_t)d_ws;
  auto alloc = [&](size_t bytes) -> void* {
    uintptr_t cur = (p + 255) & ~(uintptr_t)255;
    p = cur + bytes;
    return (void*)cur;
  };
  unsigned short* featB = (unsigned short*)alloc((size_t)NNODES * DIM * 2);  // 25.6 MB
  float* hbuf  = (float*)alloc((size_t)NNODES * DIM * 4);                    // 51.2 MB
  float* excsr = (float*)alloc((size_t)NEDGES * HEADS * 4);                  // 12.8 MB
  float* el    = (float*)alloc((size_t)NNODES * HEADS * 4);
  float* er    = (float*)alloc((size_t)NNODES * HEADS * 4);
  int* deg     = (int*)alloc((size_t)NNODES * 4);
  int* row_ptr = (int*)alloc((size_t)(NNODES + 1) * 4);
  int* cursor  = (int*)alloc((size_t)NNODES * 4);
  int* srcs    = (int*)alloc((size_t)NEDGES * 4);                            // 3.2 MB
  int* epos    = (int*)alloc((size_t)NEDGES * 4);                            // 3.2 MB

  const int EB = (NEDGES + 255) / 256;
  const int MB = (NNODES + 31) / 32;

  // ---- CSR by dst (same graph for both layers) ----
  hipMemsetAsync(deg, 0, (size_t)NNODES * 4, stream);
  deg_k<<<EB, 256, 0, stream>>>(dst, deg);
  scan_k<<<1, 1024, 0, stream>>>(deg, row_ptr, cursor, NNODES);
  scatter_k<<<EB, 256, 0, stream>>>(src, dst, cursor, srcs, epos);

  // ---- layer 1 ----
  gemm_k<<<MB, 256, 0, stream>>>(feature, W1, featB, NNODES);
  lr_k<<<NNODES, 256, 0, stream>>>(featB, al1, ar1, el, er);
  score_k<<<EB, 256, 0, stream>>>(src, dst, epos, el, er, excsr);
  agg1_k<<<NNODES, 256, 0, stream>>>(featB, excsr, row_ptr, srcs, hbuf);

  // ---- layer 2 (featB reused) ----
  gemm_k<<<MB, 256, 0, stream>>>(hbuf, W2, featB, NNODES);
  lr_k<<<NNODES, 256, 0, stream>>>(featB, al2, ar2, el, er);
  score_k<<<EB, 256, 0, stream>>>(src, dst, epos, el, er, excsr);
  agg2_k<<<NNODES, 256, 0, stream>>>(featB, excsr, row_ptr, srcs, out);
}

// Round 3
// 474.884 us; speedup vs baseline: 2.7464x; 1.3456x over previous
//
#include <hip/hip_runtime.h>
#include <hip/hip_fp16.h>
#include <math.h>
#include <stdint.h>

#define NNODES 50000
#define NEDGES 800000
#define DIM 256
#define HEADS 4
#define DH 64
#define NEG_SLOPE 0.2f

typedef _Float16 half8 __attribute__((ext_vector_type(8)));
typedef float floatx4 __attribute__((ext_vector_type(4)));

static __device__ __forceinline__ float h2f(unsigned short h) {
  __half x = *(const __half*)&h;
  return __half2float(x);
}
static __device__ __forceinline__ unsigned short f2h(float f) {
  __half x = __float2half(f);
  return *(const unsigned short*)&x;
}

// ---- W transpose + fp16 convert: WT[n][k] = (fp16)W[k][n], 256x256 ----------
__global__ __launch_bounds__(256) void wt_k(const float* __restrict__ W,
                                            _Float16* __restrict__ WT) {
  int n = blockIdx.x;
  int k = threadIdx.x;
  WT[n * 256 + k] = (_Float16)W[k * 256 + n];
}

// ---------------- GEMM: C[M,256](fp16) = A[M,256](f32) @ B[256,256] ----------
// MFMA f32_16x16x32_f16. Block = 4 waves, tile 64 rows x 256 cols (wave w owns
// cols w*64..w*64+63 == head w). K-steps of 32. A staged fp32->fp16 in LDS,
// B from pre-transposed fp16 WT[n][k].
// Fragment layouts (HW-verified m89/m91/m120):
//   A: lane holds A[m=lane&15][k=(lane>>4)*8 + j], j=0..7 (16B contiguous)
//   B: lane holds B[k=(lane>>4)*8 + j][n=lane&15]
//   C/D: col=lane&15, row=(lane>>4)*4 + reg
__global__ __launch_bounds__(256) void gemm_k(const float* __restrict__ A,
                                              const _Float16* __restrict__ BT,
                                              unsigned short* __restrict__ Cb,
                                              int M) {
  __shared__ __attribute__((aligned(16))) _Float16 Asl[64][32];
  __shared__ __attribute__((aligned(16))) _Float16 Bsl[256][32];
  int t = threadIdx.x;
  int lane = t & 63, w = t >> 6;
  int m16 = lane & 15, q = lane >> 4;
  int row0 = blockIdx.x * 64;
  floatx4 acc[4][4];
#pragma unroll
  for (int i = 0; i < 4; ++i)
#pragma unroll
    for (int j = 0; j < 4; ++j) acc[i][j] = (floatx4){0.f, 0.f, 0.f, 0.f};

  int arow = t >> 2, akoff = (t & 3) * 8;

  for (int k0 = 0; k0 < DIM; k0 += 32) {
    // stage A tile (64 x 32), fp32 -> fp16
    float4 a0 = make_float4(0.f, 0.f, 0.f, 0.f);
    float4 a1 = make_float4(0.f, 0.f, 0.f, 0.f);
    if (row0 + arow < M) {
      const float* ap = &A[(size_t)(row0 + arow) * DIM + k0 + akoff];
      a0 = *(const float4*)ap;
      a1 = *(const float4*)(ap + 4);
    }
    _Float16* al = &Asl[arow][akoff];
    al[0] = (_Float16)a0.x; al[1] = (_Float16)a0.y;
    al[2] = (_Float16)a0.z; al[3] = (_Float16)a0.w;
    al[4] = (_Float16)a1.x; al[5] = (_Float16)a1.y;
    al[6] = (_Float16)a1.z; al[7] = (_Float16)a1.w;
    // stage B tile (256 x 32): thread t = col n
    {
      const _Float16* bp = &BT[(size_t)t * 256 + k0];
      *(int4*)&Bsl[t][0] = *(const int4*)bp;
      *(int4*)&Bsl[t][8] = *(const int4*)(bp + 8);
      *(int4*)&Bsl[t][16] = *(const int4*)(bp + 16);
      *(int4*)&Bsl[t][24] = *(const int4*)(bp + 24);
    }
    __syncthreads();
    half8 af[4], bf[4];
#pragma unroll
    for (int i = 0; i < 4; ++i) af[i] = *(const half8*)&Asl[i * 16 + m16][q * 8];
#pragma unroll
    for (int i = 0; i < 4; ++i)
      bf[i] = *(const half8*)&Bsl[w * 64 + i * 16 + m16][q * 8];
#pragma unroll
    for (int mi = 0; mi < 4; ++mi)
#pragma unroll
      for (int ni = 0; ni < 4; ++ni)
        acc[mi][ni] = __builtin_amdgcn_mfma_f32_16x16x32_f16(
            af[mi], bf[ni], acc[mi][ni], 0, 0, 0);
    __syncthreads();
  }
#pragma unroll
  for (int mi = 0; mi < 4; ++mi) {
#pragma unroll
    for (int r = 0; r < 4; ++r) {
      int row = row0 + mi * 16 + q * 4 + r;
      if (row < M) {
#pragma unroll
        for (int ni = 0; ni < 4; ++ni)
          Cb[(size_t)row * DIM + w * 64 + ni * 16 + m16] = f2h(acc[mi][ni][r]);
      }
    }
  }
}

// --------------- el/er: per (node, head) dot of feat(fp16) with al/ar --------
// 4 nodes/block (one per wave); lane covers 4 consecutive feature dims.
__global__ __launch_bounds__(256) void lr_k(const unsigned short* __restrict__ feat,
                                            const float* __restrict__ al,
                                            const float* __restrict__ ar,
                                            float* __restrict__ el,
                                            float* __restrict__ er) {
  int lane = threadIdx.x & 63;
  int w = threadIdx.x >> 6;
  int n = blockIdx.x * 4 + w;
  if (n >= NNODES) return;
  ushort4 u = *(const ushort4*)&feat[(size_t)n * DIM + lane * 4];
  float4 av = *(const float4*)&al[lane * 4];
  float4 bv = *(const float4*)&ar[lane * 4];
  float f0 = h2f(u.x), f1 = h2f(u.y), f2 = h2f(u.z), f3 = h2f(u.w);
  float a = f0 * av.x + f1 * av.y + f2 * av.z + f3 * av.w;
  float b = f0 * bv.x + f1 * bv.y + f2 * bv.z + f3 * bv.w;
#pragma unroll
  for (int off = 1; off < 16; off <<= 1) {
    a += __shfl_xor(a, off, 64);
    b += __shfl_xor(b, off, 64);
  }
  if ((lane & 15) == 0) {
    int h = lane >> 4;
    el[n * HEADS + h] = a;
    er[n * HEADS + h] = b;
  }
}

// ---------------- CSR build ----------------
__global__ __launch_bounds__(256) void deg_k(const int* __restrict__ dst,
                                             int* __restrict__ deg) {
  int e = blockIdx.x * 256 + threadIdx.x;
  if (e < NEDGES) atomicAdd(&deg[dst[e]], 1);
}

__global__ __launch_bounds__(1024) void scan_k(const int* __restrict__ deg,
                                               int* __restrict__ row_ptr,
                                               int* __restrict__ cursor, int n) {
  __shared__ int wsum[16];
  __shared__ int wpref[16];
  int t = threadIdx.x, lane = t & 63, w = t >> 6;
  int running = 0;
  for (int base = 0; base < n; base += 4096) {
    int idx0 = base + t * 4;
    int4 v = make_int4(0, 0, 0, 0);
    if (idx0 + 3 < n) v = *(const int4*)&deg[idx0];
    else {
      if (idx0 < n) v.x = deg[idx0];
      if (idx0 + 1 < n) v.y = deg[idx0 + 1];
      if (idx0 + 2 < n) v.z = deg[idx0 + 2];
    }
    int s0 = v.x, s1 = s0 + v.y, s2 = s1 + v.z, s3 = s2 + v.w;
    int incl = s3;
#pragma unroll
    for (int off = 1; off < 64; off <<= 1) {
      int u = __shfl_up(incl, off, 64);
      if (lane >= off) incl += u;
    }
    if (lane == 63) wsum[w] = incl;
    __syncthreads();
    if (w == 0 && lane < 16) {
      int x = wsum[lane];
#pragma unroll
      for (int off = 1; off < 16; off <<= 1) {
        int u = __shfl_up(x, off, 64);
        if (lane >= off) x += u;
      }
      wpref[lane] = x;
    }
    __syncthreads();
    int wbase = (w == 0) ? 0 : wpref[w - 1];
    int texcl = incl - s3 + wbase + running;
    if (idx0 < n)     { row_ptr[idx0]     = texcl;      cursor[idx0]     = texcl; }
    if (idx0 + 1 < n) { row_ptr[idx0 + 1] = texcl + s0; cursor[idx0 + 1] = texcl + s0; }
    if (idx0 + 2 < n) { row_ptr[idx0 + 2] = texcl + s1; cursor[idx0 + 2] = texcl + s1; }
    if (idx0 + 3 < n) { row_ptr[idx0 + 3] = texcl + s2; cursor[idx0 + 3] = texcl + s2; }
    int tot = wpref[15];
    __syncthreads();
    running += tot;
  }
  if (t == 0) row_ptr[n] = running;
}

__global__ __launch_bounds__(256) void scatter_k(const int* __restrict__ src,
                                                 const int* __restrict__ dst,
                                                 int* __restrict__ cursor,
                                                 int* __restrict__ srcs,
                                                 int* __restrict__ epos) {
  int e = blockIdx.x * 256 + threadIdx.x;
  if (e < NEDGES) {
    int pos = atomicAdd(&cursor[dst[e]], 1);
    srcs[pos] = src[e];
    epos[e] = pos;
  }
}

// -------- edge scores: ex = exp(leaky_relu(el[src]+er[dst])) in CSR order ----
// segment_max dropped: scores are O(1), fp32 exp safe, alpha identical.
__global__ __launch_bounds__(256) void score_k(const int* __restrict__ src,
                                               const int* __restrict__ dst,
                                               const int* __restrict__ epos,
                                               const float* __restrict__ el,
                                               const float* __restrict__ er,
                                               float* __restrict__ excsr) {
  int e = blockIdx.x * 256 + threadIdx.x;
  if (e >= NEDGES) return;
  int s = src[e], d = dst[e];
  float4 l = *(const float4*)&el[s * HEADS];
  float4 r = *(const float4*)&er[d * HEADS];
  float4 o;
  float v;
  v = l.x + r.x; v = v > 0.f ? v : NEG_SLOPE * v; o.x = __expf(v);
  v = l.y + r.y; v = v > 0.f ? v : NEG_SLOPE * v; o.y = __expf(v);
  v = l.z + r.z; v = v > 0.f ? v : NEG_SLOPE * v; o.z = __expf(v);
  v = l.w + r.w; v = v > 0.f ? v : NEG_SLOPE * v; o.w = __expf(v);
  *(float4*)&excsr[(size_t)epos[e] * HEADS] = o;
}

// ---------------- aggregation (gather over CSR), fp16 feat -------------------
#define AGG_BODY(feat, excsr, row_ptr, srcs)                                     \
  int n = blockIdx.x;                                                            \
  int lane = threadIdx.x & 63;                                                   \
  int w = threadIdx.x >> 6;                                                      \
  int li = lane & 31;                                                            \
  int half_ = lane >> 5;                                                         \
  int beg = row_ptr[n], end = row_ptr[n + 1];                                    \
  float accx = 0.f, accy = 0.f, sume = 0.f;                                      \
  for (int c0 = beg; c0 < end; c0 += 16) {                                       \
    int s_l = 0;                                                                 \
    float e_l = 0.f;                                                             \
    if (lane < 16 && c0 + lane < end) {                                          \
      s_l = srcs[c0 + lane];                                                     \
      e_l = excsr[(size_t)(c0 + lane) * HEADS + w];                              \
    }                                                                            \
    _Pragma("unroll")                                                            \
    for (int j = 0; j < 8; ++j) {                                                \
      int idx = 2 * j + half_;                                                   \
      int s = __shfl(s_l, idx, 64);                                              \
      float a = __shfl(e_l, idx, 64);                                            \
      ushort2 u = *(const ushort2*)&feat[(size_t)s * DIM + w * DH + li * 2];     \
      accx += h2f(u.x) * a;                                                      \
      accy += h2f(u.y) * a;                                                      \
      sume += a;                                                                 \
    }                                                                            \
  }                                                                              \
  accx += __shfl_xor(accx, 32, 64);                                              \
  accy += __shfl_xor(accy, 32, 64);                                              \
  sume += __shfl_xor(sume, 32, 64);                                              \
  float inv = 1.f / fmaxf(sume, 1e-9f);

__global__ __launch_bounds__(256) void agg1_k(const unsigned short* __restrict__ feat,
                                              const float* __restrict__ excsr,
                                              const int* __restrict__ row_ptr,
                                              const int* __restrict__ srcs,
                                              float* __restrict__ hout) {
  AGG_BODY(feat, excsr, row_ptr, srcs)
  if (half_ == 0) {
    float vx = accx * inv, vy = accy * inv;
    vx = vx > 0.f ? vx : (__expf(vx) - 1.f);  // ELU
    vy = vy > 0.f ? vy : (__expf(vy) - 1.f);
    *(float2*)&hout[(size_t)n * DIM + w * DH + li * 2] = make_float2(vx, vy);
  }
}

__global__ __launch_bounds__(256) void agg2_k(const unsigned short* __restrict__ feat,
                                              const float* __restrict__ excsr,
                                              const int* __restrict__ row_ptr,
                                              const int* __restrict__ srcs,
                                              float* __restrict__ out) {
  __shared__ float sm[HEADS][DH];
  AGG_BODY(feat, excsr, row_ptr, srcs)
  if (half_ == 0) {
    sm[w][li * 2] = accx * inv;
    sm[w][li * 2 + 1] = accy * inv;
  }
  __syncthreads();
  if (w == 0) {
    float m = (sm[0][lane] + sm[1][lane] + sm[2][lane] + sm[3][lane]) * 0.25f;
    out[(size_t)n * DH + lane] = m;
  }
}

extern "C" void kernel_launch(void* const* d_in, const int* in_sizes, int n_in,
                              void* d_out, int out_size, void* d_ws, size_t ws_size,
                              hipStream_t stream) {
  const float* feature = (const float*)d_in[0];
  const float* W1 = (const float*)d_in[1];
  const float* al1 = (const float*)d_in[2];
  const float* ar1 = (const float*)d_in[3];
  const float* W2 = (const float*)d_in[4];
  const float* al2 = (const float*)d_in[5];
  const float* ar2 = (const float*)d_in[6];
  const int* src = (const int*)d_in[7];
  const int* dst = (const int*)d_in[8];
  float* out = (float*)d_out;

  uintptr_t p = (uintptr_t)d_ws;
  auto alloc = [&](size_t bytes) -> void* {
    uintptr_t cur = (p + 255) & ~(uintptr_t)255;
    p = cur + bytes;
    return (void*)cur;
  };
  unsigned short* featH = (unsigned short*)alloc((size_t)NNODES * DIM * 2);  // 25.6 MB
  float* hbuf  = (float*)alloc((size_t)NNODES * DIM * 4);                    // 51.2 MB
  float* excsr = (float*)alloc((size_t)NEDGES * HEADS * 4);                  // 12.8 MB
  _Float16* WT1 = (_Float16*)alloc((size_t)256 * 256 * 2);
  _Float16* WT2 = (_Float16*)alloc((size_t)256 * 256 * 2);
  float* el    = (float*)alloc((size_t)NNODES * HEADS * 4);
  float* er    = (float*)alloc((size_t)NNODES * HEADS * 4);
  int* deg     = (int*)alloc((size_t)NNODES * 4);
  int* row_ptr = (int*)alloc((size_t)(NNODES + 1) * 4);
  int* cursor  = (int*)alloc((size_t)NNODES * 4);
  int* srcs    = (int*)alloc((size_t)NEDGES * 4);
  int* epos    = (int*)alloc((size_t)NEDGES * 4);

  const int EB = (NEDGES + 255) / 256;
  const int MB = (NNODES + 63) / 64;
  const int LB = (NNODES + 3) / 4;

  // ---- weight transpose/convert + CSR build ----
  wt_k<<<256, 256, 0, stream>>>(W1, WT1);
  wt_k<<<256, 256, 0, stream>>>(W2, WT2);
  hipMemsetAsync(deg, 0, (size_t)NNODES * 4, stream);
  deg_k<<<EB, 256, 0, stream>>>(dst, deg);
  scan_k<<<1, 1024, 0, stream>>>(deg, row_ptr, cursor, NNODES);
  scatter_k<<<EB, 256, 0, stream>>>(src, dst, cursor, srcs, epos);

  // ---- layer 1 ----
  gemm_k<<<MB, 256, 0, stream>>>(feature, WT1, featH, NNODES);
  lr_k<<<LB, 256, 0, stream>>>(featH, al1, ar1, el, er);
  score_k<<<EB, 256, 0, stream>>>(src, dst, epos, el, er, excsr);
  agg1_k<<<NNODES, 256, 0, stream>>>(featH, excsr, row_ptr, srcs, hbuf);

  // ---- layer 2 ----
  gemm_k<<<MB, 256, 0, stream>>>(hbuf, WT2, featH, NNODES);
  lr_k<<<LB, 256, 0, stream>>>(featH, al2, ar2, el, er);
  score_k<<<EB, 256, 0, stream>>>(src, dst, epos, el, er, excsr);
  agg2_k<<<NNODES, 256, 0, stream>>>(featH, excsr, row_ptr, srcs, out);
}

// Round 4
// 404.879 us; speedup vs baseline: 3.2213x; 1.1729x over previous
//
#include <hip/hip_runtime.h>
#include <hip/hip_fp16.h>
#include <math.h>
#include <stdint.h>

#define NNODES 50000
#define NEDGES 800000
#define DIM 256
#define HEADS 4
#define DH 64
#define NEG_SLOPE 0.2f

typedef _Float16 half8 __attribute__((ext_vector_type(8)));
typedef float floatx4 __attribute__((ext_vector_type(4)));

static __device__ __forceinline__ float h2f(unsigned short h) {
  __half x = *(const __half*)&h;
  return __half2float(x);
}
static __device__ __forceinline__ unsigned short f2h(float f) {
  __half x = __float2half(f);
  return *(const unsigned short*)&x;
}

// ---- W transpose + fp16 convert: WT[n][k] = (fp16)W[k][n], 256x256 ----------
__global__ __launch_bounds__(256) void wt_k(const float* __restrict__ W,
                                            _Float16* __restrict__ WT) {
  int n = blockIdx.x;
  int k = threadIdx.x;
  WT[n * 256 + k] = (_Float16)W[k * 256 + n];
}

// ------- GEMM + fused el/er: C[M,256](fp16) = A[M,256] @ B ; el/er[M,4] ------
// MFMA f32_16x16x32_f16. Block = 4 waves, tile 64 rows x 256 cols (wave w owns
// cols w*64.. == head w). A staged (fp32->fp16 convert, or raw fp16 copy);
// B from pre-transposed fp16 WT[n][k].
// Fragment layouts (HW-verified m89/m91/m120):
//   A: lane holds A[m=lane&15][k=(lane>>4)*8 + j], j=0..7
//   B: lane holds B[k=(lane>>4)*8 + j][n=lane&15]
//   C/D: col=lane&15, row=(lane>>4)*4 + reg
// Epilogue: el[row][w] = sum_d C[row][w*64+d]*al[w][d] (fp32 acc, pre-rounding),
// reduced over the 16-lane m16 group via shfl_xor; same for er.
template <typename AT>
__global__ __launch_bounds__(256) void gemm_k(const AT* __restrict__ A,
                                              const _Float16* __restrict__ BT,
                                              const float* __restrict__ alw,
                                              const float* __restrict__ arw,
                                              unsigned short* __restrict__ Cb,
                                              float* __restrict__ el,
                                              float* __restrict__ er, int M) {
  __shared__ __attribute__((aligned(16))) _Float16 Asl[64][32];
  __shared__ __attribute__((aligned(16))) _Float16 Bsl[256][32];
  int t = threadIdx.x;
  int lane = t & 63, w = t >> 6;
  int m16 = lane & 15, q = lane >> 4;
  int row0 = blockIdx.x * 64;
  floatx4 acc[4][4];
#pragma unroll
  for (int i = 0; i < 4; ++i)
#pragma unroll
    for (int j = 0; j < 4; ++j) acc[i][j] = (floatx4){0.f, 0.f, 0.f, 0.f};

  float alv[4], arv[4];
#pragma unroll
  for (int ni = 0; ni < 4; ++ni) {
    alv[ni] = alw[w * 64 + ni * 16 + m16];
    arv[ni] = arw[w * 64 + ni * 16 + m16];
  }

  int arow = t >> 2, akoff = (t & 3) * 8;

  for (int k0 = 0; k0 < DIM; k0 += 32) {
    if constexpr (sizeof(AT) == 4) {
      float4 x0 = make_float4(0.f, 0.f, 0.f, 0.f);
      float4 x1 = make_float4(0.f, 0.f, 0.f, 0.f);
      if (row0 + arow < M) {
        const float* ap = (const float*)&A[(size_t)(row0 + arow) * DIM + k0 + akoff];
        x0 = *(const float4*)ap;
        x1 = *(const float4*)(ap + 4);
      }
      _Float16* as = &Asl[arow][akoff];
      as[0] = (_Float16)x0.x; as[1] = (_Float16)x0.y;
      as[2] = (_Float16)x0.z; as[3] = (_Float16)x0.w;
      as[4] = (_Float16)x1.x; as[5] = (_Float16)x1.y;
      as[6] = (_Float16)x1.z; as[7] = (_Float16)x1.w;
    } else {
      int4 x = make_int4(0, 0, 0, 0);
      if (row0 + arow < M)
        x = *(const int4*)&A[(size_t)(row0 + arow) * DIM + k0 + akoff];
      *(int4*)&Asl[arow][akoff] = x;
    }
    {
      const _Float16* bp = &BT[(size_t)t * 256 + k0];
      *(int4*)&Bsl[t][0] = *(const int4*)bp;
      *(int4*)&Bsl[t][8] = *(const int4*)(bp + 8);
      *(int4*)&Bsl[t][16] = *(const int4*)(bp + 16);
      *(int4*)&Bsl[t][24] = *(const int4*)(bp + 24);
    }
    __syncthreads();
    half8 af[4], bf[4];
#pragma unroll
    for (int i = 0; i < 4; ++i) af[i] = *(const half8*)&Asl[i * 16 + m16][q * 8];
#pragma unroll
    for (int i = 0; i < 4; ++i)
      bf[i] = *(const half8*)&Bsl[w * 64 + i * 16 + m16][q * 8];
#pragma unroll
    for (int mi = 0; mi < 4; ++mi)
#pragma unroll
      for (int ni = 0; ni < 4; ++ni)
        acc[mi][ni] = __builtin_amdgcn_mfma_f32_16x16x32_f16(
            af[mi], bf[ni], acc[mi][ni], 0, 0, 0);
    __syncthreads();
  }
  // fused el/er epilogue
#pragma unroll
  for (int mi = 0; mi < 4; ++mi) {
#pragma unroll
    for (int r = 0; r < 4; ++r) {
      float pl = acc[mi][0][r] * alv[0] + acc[mi][1][r] * alv[1] +
                 acc[mi][2][r] * alv[2] + acc[mi][3][r] * alv[3];
      float pr = acc[mi][0][r] * arv[0] + acc[mi][1][r] * arv[1] +
                 acc[mi][2][r] * arv[2] + acc[mi][3][r] * arv[3];
#pragma unroll
      for (int off = 1; off < 16; off <<= 1) {
        pl += __shfl_xor(pl, off, 64);
        pr += __shfl_xor(pr, off, 64);
      }
      int row = row0 + mi * 16 + q * 4 + r;
      if (m16 == 0 && row < M) {
        el[row * HEADS + w] = pl;
        er[row * HEADS + w] = pr;
      }
    }
  }
  // C store (fp16)
#pragma unroll
  for (int mi = 0; mi < 4; ++mi) {
#pragma unroll
    for (int r = 0; r < 4; ++r) {
      int row = row0 + mi * 16 + q * 4 + r;
      if (row < M) {
#pragma unroll
        for (int ni = 0; ni < 4; ++ni)
          Cb[(size_t)row * DIM + w * 64 + ni * 16 + m16] = f2h(acc[mi][ni][r]);
      }
    }
  }
}

// ---------------- CSR build ----------------
__global__ __launch_bounds__(256) void deg_k(const int* __restrict__ dst,
                                             int* __restrict__ deg) {
  int e = blockIdx.x * 256 + threadIdx.x;
  if (e < NEDGES) atomicAdd(&deg[dst[e]], 1);
}

__global__ __launch_bounds__(1024) void scan_k(const int* __restrict__ deg,
                                               int* __restrict__ row_ptr,
                                               int* __restrict__ cursor, int n) {
  __shared__ int wsum[16];
  __shared__ int wpref[16];
  int t = threadIdx.x, lane = t & 63, w = t >> 6;
  int running = 0;
  for (int base = 0; base < n; base += 4096) {
    int idx0 = base + t * 4;
    int4 v = make_int4(0, 0, 0, 0);
    if (idx0 + 3 < n) v = *(const int4*)&deg[idx0];
    else {
      if (idx0 < n) v.x = deg[idx0];
      if (idx0 + 1 < n) v.y = deg[idx0 + 1];
      if (idx0 + 2 < n) v.z = deg[idx0 + 2];
    }
    int s0 = v.x, s1 = s0 + v.y, s2 = s1 + v.z, s3 = s2 + v.w;
    int incl = s3;
#pragma unroll
    for (int off = 1; off < 64; off <<= 1) {
      int u = __shfl_up(incl, off, 64);
      if (lane >= off) incl += u;
    }
    if (lane == 63) wsum[w] = incl;
    __syncthreads();
    if (w == 0 && lane < 16) {
      int x = wsum[lane];
#pragma unroll
      for (int off = 1; off < 16; off <<= 1) {
        int u = __shfl_up(x, off, 64);
        if (lane >= off) x += u;
      }
      wpref[lane] = x;
    }
    __syncthreads();
    int wbase = (w == 0) ? 0 : wpref[w - 1];
    int texcl = incl - s3 + wbase + running;
    if (idx0 < n)     { row_ptr[idx0]     = texcl;      cursor[idx0]     = texcl; }
    if (idx0 + 1 < n) { row_ptr[idx0 + 1] = texcl + s0; cursor[idx0 + 1] = texcl + s0; }
    if (idx0 + 2 < n) { row_ptr[idx0 + 2] = texcl + s1; cursor[idx0 + 2] = texcl + s1; }
    if (idx0 + 3 < n) { row_ptr[idx0 + 3] = texcl + s2; cursor[idx0 + 3] = texcl + s2; }
    int tot = wpref[15];
    __syncthreads();
    running += tot;
  }
  if (t == 0) row_ptr[n] = running;
}

// scatter: srcoff[pos] = byte offset of the source node's fp16 feat row.
__global__ __launch_bounds__(256) void scatter_k(const int* __restrict__ src,
                                                 const int* __restrict__ dst,
                                                 int* __restrict__ cursor,
                                                 int* __restrict__ srcoff) {
  int e = blockIdx.x * 256 + threadIdx.x;
  if (e < NEDGES) {
    int pos = atomicAdd(&cursor[dst[e]], 1);
    srcoff[pos] = src[e] << 9;  // * 512 bytes (256 fp16)
  }
}

// ---------- fused score + softmax + aggregation (gather over CSR) ------------
// One wave per node (block = 4 waves = 4 nodes). lane*4 = global feature idx,
// head h = lane>>4. Per 16-edge chunk: lanes 0-15 preload srcoff; lane L
// computes alpha of edge c0+(L>>2), head L&3 inline from el-gather (800 KB
// L2-resident) + er[n]; per edge one ushort4 load/lane covers the full 512 B
// feat row. alpha is uniform within a head group => sume needs no reduction.
// segment_max dropped: scores O(1), fp32 exp safe, alpha identical.
template <int MODE>  // 1 = ELU -> fp16 hidden; 2 = mean over heads -> fp32 out
__global__ __launch_bounds__(256) void agg_k(const unsigned short* __restrict__ feat,
                                             const float* __restrict__ el,
                                             const float* __restrict__ er,
                                             const int* __restrict__ row_ptr,
                                             const int* __restrict__ srcoff,
                                             void* __restrict__ outp) {
  int lane = threadIdx.x & 63;
  int w = threadIdx.x >> 6;
  int n = blockIdx.x * 4 + w;
  if (n >= NNODES) return;
  int h = lane >> 4;
  int hsel = lane & 3;
  int esel = lane >> 2;
  int beg = row_ptr[n], end = row_ptr[n + 1];
  float erv = er[n * HEADS + hsel];
  int laneByte = lane * 8;
  const char* fb = (const char*)feat;
  const char* elb = (const char*)el;
  float a0 = 0.f, a1 = 0.f, a2 = 0.f, a3 = 0.f, sume = 0.f;
  for (int c0 = beg; c0 < end; c0 += 16) {
    int soff = 0;
    if (lane < 16 && c0 + lane < end) soff = srcoff[c0 + lane];
    float av = 0.f;
    if (c0 + esel < end) {
      int sE = __shfl(soff, esel, 64);
      float elv = *(const float*)(elb + (sE >> 5) + hsel * 4);  // el[s][hsel]
      float v = elv + erv;
      v = v > 0.f ? v : NEG_SLOPE * v;
      av = __expf(v);
    }
    for (int j4 = 0; j4 < 16; j4 += 4) {
      if (c0 + j4 >= end) break;  // wave-uniform branch
#pragma unroll
      for (int jj = 0; jj < 4; ++jj) {
        int j = j4 + jj;
        int sB = __shfl(soff, j, 64);
        float a = __shfl(av, 4 * j + h, 64);
        ushort4 u = *(const ushort4*)(fb + (sB + laneByte));
        a0 += h2f(u.x) * a;
        a1 += h2f(u.y) * a;
        a2 += h2f(u.z) * a;
        a3 += h2f(u.w) * a;
        sume += a;
      }
    }
  }
  float inv = 1.f / fmaxf(sume, 1e-9f);
  a0 *= inv; a1 *= inv; a2 *= inv; a3 *= inv;
  if (MODE == 1) {
    a0 = a0 > 0.f ? a0 : (__expf(a0) - 1.f);
    a1 = a1 > 0.f ? a1 : (__expf(a1) - 1.f);
    a2 = a2 > 0.f ? a2 : (__expf(a2) - 1.f);
    a3 = a3 > 0.f ? a3 : (__expf(a3) - 1.f);
    ushort4 o;
    o.x = f2h(a0); o.y = f2h(a1); o.z = f2h(a2); o.w = f2h(a3);
    *(ushort4*)((char*)outp + (size_t)n * 512 + laneByte) = o;
  } else {
    a0 += __shfl_xor(a0, 16, 64); a0 += __shfl_xor(a0, 32, 64);
    a1 += __shfl_xor(a1, 16, 64); a1 += __shfl_xor(a1, 32, 64);
    a2 += __shfl_xor(a2, 16, 64); a2 += __shfl_xor(a2, 32, 64);
    a3 += __shfl_xor(a3, 16, 64); a3 += __shfl_xor(a3, 32, 64);
    if (lane < 16) {
      float4 o = make_float4(a0 * 0.25f, a1 * 0.25f, a2 * 0.25f, a3 * 0.25f);
      *(float4*)((float*)outp + (size_t)n * 64 + lane * 4) = o;
    }
  }
}

extern "C" void kernel_launch(void* const* d_in, const int* in_sizes, int n_in,
                              void* d_out, int out_size, void* d_ws, size_t ws_size,
                              hipStream_t stream) {
  const float* feature = (const float*)d_in[0];
  const float* W1 = (const float*)d_in[1];
  const float* al1 = (const float*)d_in[2];
  const float* ar1 = (const float*)d_in[3];
  const float* W2 = (const float*)d_in[4];
  const float* al2 = (const float*)d_in[5];
  const float* ar2 = (const float*)d_in[6];
  const int* src = (const int*)d_in[7];
  const int* dst = (const int*)d_in[8];
  float* out = (float*)d_out;

  uintptr_t p = (uintptr_t)d_ws;
  auto alloc = [&](size_t bytes) -> void* {
    uintptr_t cur = (p + 255) & ~(uintptr_t)255;
    p = cur + bytes;
    return (void*)cur;
  };
  unsigned short* featH = (unsigned short*)alloc((size_t)NNODES * DIM * 2);  // 25.6 MB
  unsigned short* hidH  = (unsigned short*)alloc((size_t)NNODES * DIM * 2);  // 25.6 MB
  _Float16* WT1 = (_Float16*)alloc((size_t)256 * 256 * 2);
  _Float16* WT2 = (_Float16*)alloc((size_t)256 * 256 * 2);
  float* el    = (float*)alloc((size_t)NNODES * HEADS * 4);
  float* er    = (float*)alloc((size_t)NNODES * HEADS * 4);
  int* deg     = (int*)alloc((size_t)NNODES * 4);
  int* row_ptr = (int*)alloc((size_t)(NNODES + 1) * 4);
  int* cursor  = (int*)alloc((size_t)NNODES * 4);
  int* srcoff  = (int*)alloc((size_t)NEDGES * 4);

  const int EB = (NEDGES + 255) / 256;
  const int MB = (NNODES + 63) / 64;
  const int AB = (NNODES + 3) / 4;

  // ---- weight transpose/convert + CSR build (CSR shared by both layers) ----
  wt_k<<<256, 256, 0, stream>>>(W1, WT1);
  wt_k<<<256, 256, 0, stream>>>(W2, WT2);
  hipMemsetAsync(deg, 0, (size_t)NNODES * 4, stream);
  deg_k<<<EB, 256, 0, stream>>>(dst, deg);
  scan_k<<<1, 1024, 0, stream>>>(deg, row_ptr, cursor, NNODES);
  scatter_k<<<EB, 256, 0, stream>>>(src, dst, cursor, srcoff);

  // ---- layer 1: GEMM(+el/er) -> fused score/softmax/agg (+ELU, fp16) ----
  gemm_k<float><<<MB, 256, 0, stream>>>(feature, WT1, al1, ar1, featH, el, er, NNODES);
  agg_k<1><<<AB, 256, 0, stream>>>(featH, el, er, row_ptr, srcoff, hidH);

  // ---- layer 2: GEMM(+el/er) -> fused agg + head-mean -> d_out ----
  gemm_k<_Float16><<<MB, 256, 0, stream>>>((const _Float16*)hidH, WT2, al2, ar2,
                                           featH, el, er, NNODES);
  agg_k<2><<<AB, 256, 0, stream>>>(featH, el, er, row_ptr, srcoff, out);
}